// Round 4
// baseline (203.008 us; speedup 1.0000x reference)
//
#include <hip/hip_runtime.h>
#include <stdint.h>

// B=2, S=2048, D=1024, H=16, HD=64. fp32 in/out, bf16 MFMA internally.

typedef __attribute__((ext_vector_type(8))) short short8;
typedef __attribute__((ext_vector_type(4))) float floatx4;

#define S_LEN 2048
#define D_DIM 1024
#define NH 16
#define HD 64
#define L2E 1.44269504088896340736f

__device__ __forceinline__ short f2bf(float f) {
    uint32_t u = __builtin_bit_cast(uint32_t, f);
    uint32_t r = u + 0x7fffu + ((u >> 16) & 1u);   // RNE
    return (short)(r >> 16);
}
__device__ __forceinline__ uint32_t pack2(float a, float b) {
#if __has_builtin(__builtin_amdgcn_cvt_pk_bf16_f32)
    auto v = __builtin_amdgcn_cvt_pk_bf16_f32(a, b);
    uint32_t r; __builtin_memcpy(&r, &v, sizeof(r)); return r;
#else
    return (uint32_t)(uint16_t)f2bf(a) | ((uint32_t)(uint16_t)f2bf(b) << 16);
#endif
}
__device__ __forceinline__ void gll16(const void* g, void* l) {
    __builtin_amdgcn_global_load_lds(
        (const __attribute__((address_space(1))) void*)g,
        (__attribute__((address_space(3))) void*)l, 16, 0, 0);
}

// ---------------- cast X: fp32 -> bf16 ----------------
__global__ __launch_bounds__(256) void castx_kernel(const float* __restrict__ X,
                                                    short* __restrict__ Xb) {
    int i = blockIdx.x * 256 + threadIdx.x;
    const float4 v = *(const float4*)(X + (size_t)i * 4);
    uint2 o;
    o.x = pack2(v.x, v.y);
    o.y = pack2(v.z, v.w);
    *(uint2*)(Xb + (size_t)i * 4) = o;
}

// ------------- transpose+cast all 4 weights in one launch -------------
__global__ __launch_bounds__(256) void tcast4_kernel(const float* __restrict__ Wq,
                                                     const float* __restrict__ Wk,
                                                     const float* __restrict__ Wv,
                                                     const float* __restrict__ Wo,
                                                     short* __restrict__ WqkvT,
                                                     short* __restrict__ WoT) {
    const int z = blockIdx.z;
    const float* W = (z == 0) ? Wq : (z == 1) ? Wk : (z == 2) ? Wv : Wo;
    short* WT = (z < 3) ? (WqkvT + (size_t)z * 1024 * 1024) : WoT;
    __shared__ float tile[32][33];
    const int bx = blockIdx.x * 32;
    const int by = blockIdx.y * 32;
    const int tx = threadIdx.x, ty = threadIdx.y;    // 32 x 8
    for (int i = 0; i < 32; i += 8)
        tile[ty + i][tx] = W[(size_t)(bx + ty + i) * D_DIM + by + tx];
    __syncthreads();
    for (int i = 0; i < 32; i += 8)
        WT[(size_t)(by + ty + i) * D_DIM + bx + tx] = f2bf(tile[tx][ty + i]);
}

// ---------------- GEMM mainloop (m97 recipe) ----------------
__device__ __forceinline__ void gemm_main(const short* __restrict__ A,
                                          const short* __restrict__ BT,
                                          short* As, short* Bs,
                                          int m0, int n0, floatx4 (&acc)[4][4],
                                          int tid) {
    const int lane = tid & 63, ln = lane & 15, quad = lane >> 4;
    const int wave = tid >> 6;
    const int mw = (wave & 1) * 64, nw = (wave >> 1) * 64;
    for (int k0 = 0; k0 < D_DIM; k0 += 64) {
        __syncthreads();
        for (int t = 0; t < 4; t++) {
            const int c = t * 256 + tid;
            const int row = c >> 3, pos = c & 7, src = pos ^ (row & 7);
            gll16(A  + (size_t)(m0 + row) * D_DIM + k0 + src * 8, As + c * 8);
            gll16(BT + (size_t)(n0 + row) * D_DIM + k0 + src * 8, Bs + c * 8);
        }
        __syncthreads();
        for (int ks = 0; ks < 2; ks++) {
            short8 a[4], b[4];
            for (int i = 0; i < 4; i++) {
                const int row = mw + i * 16 + ln;
                a[i] = *(const short8*)(As + row * 64 + (((ks * 4 + quad) ^ (ln & 7)) * 8));
            }
            for (int j = 0; j < 4; j++) {
                const int row = nw + j * 16 + ln;
                b[j] = *(const short8*)(Bs + row * 64 + (((ks * 4 + quad) ^ (ln & 7)) * 8));
            }
            for (int i = 0; i < 4; i++)
                for (int j = 0; j < 4; j++)
                    acc[i][j] = __builtin_amdgcn_mfma_f32_16x16x32_bf16(a[i], b[j], acc[i][j], 0, 0, 0);
        }
    }
}

// fused QKV: grid (32, 24). Epilogue transposes through LDS for coalesced
// 16B stores. Q is pre-scaled by log2(e) so attention uses exp2 directly.
__global__ __launch_bounds__(256) void gemm_qkv_kernel(const short* __restrict__ Xb,
                                                       const short* __restrict__ WT,
                                                       short* __restrict__ Qb,
                                                       short* __restrict__ Kb,
                                                       short* __restrict__ Vtb) {
    __shared__ __align__(16) short LB[2 * 128 * 64];   // As | Bs, reused as T[128][128]
    short* As = LB;
    short* Bs = LB + 128 * 64;
    const int m0 = blockIdx.x * 128, n0 = blockIdx.y * 128;
    floatx4 acc[4][4] = {};
    gemm_main(Xb, WT, As, Bs, m0, n0, acc, threadIdx.x);

    const int tid = threadIdx.x, wave = tid >> 6, lane = tid & 63;
    const int ln = lane & 15, quad = lane >> 4;
    const int mw = (wave & 1) * 64, nw = (wave >> 1) * 64;
    const int nsel = n0 >> 10;              // 0:Q 1:K 2:V
    const int hb = (n0 & 1023) >> 6;        // first head in this tile
    const int bb = m0 >> 11, s0 = m0 & (S_LEN - 1);
    short* T = LB;

    __syncthreads();   // all waves done reading As/Bs
    if (nsel < 2) {
        const float qs = (nsel == 0) ? L2E : 1.f;
        // T[token][feat]
        for (int i = 0; i < 4; i++)
            for (int j = 0; j < 4; j++)
                for (int r = 0; r < 4; r++)
                    T[(mw + i * 16 + quad * 4 + r) * 128 + nw + j * 16 + ln] =
                        f2bf(acc[i][j][r] * qs);
        __syncthreads();
        short* outB = (nsel == 0) ? Qb : Kb;
        for (int it = 0; it < 8; it++) {
            const int g = it * 256 + tid;
            const int tl = g >> 4, hh = (g >> 3) & 1, sg = g & 7;
            const short8 v = *(const short8*)(T + tl * 128 + hh * 64 + sg * 8);
            *(short8*)(outB + (((size_t)(bb * NH + hb + hh)) * S_LEN + s0 + tl) * HD + sg * 8) = v;
        }
    } else {
        // T[feat][token] (pack 4 consecutive tokens along r)
        for (int i = 0; i < 4; i++)
            for (int j = 0; j < 4; j++) {
                uint2 u;
                u.x = pack2(acc[i][j][0], acc[i][j][1]);
                u.y = pack2(acc[i][j][2], acc[i][j][3]);
                *(uint2*)(T + (nw + j * 16 + ln) * 128 + mw + i * 16 + quad * 4) = u;
            }
        __syncthreads();
        for (int it = 0; it < 8; it++) {
            const int g = it * 256 + tid;
            const int f = g >> 4, tc = g & 15;
            const short8 v = *(const short8*)(T + f * 128 + tc * 8);
            *(short8*)(Vtb + (((size_t)(bb * NH + hb + (f >> 6))) * HD + (f & 63)) * S_LEN
                       + s0 + tc * 8) = v;
        }
    }
}

// output projection: grid (32, 8)
__global__ __launch_bounds__(256) void gemm_out_kernel(const short* __restrict__ Cb,
                                                       const short* __restrict__ WoT,
                                                       float* __restrict__ out,
                                                       const float* __restrict__ bias) {
    __shared__ __align__(16) short LB[2 * 128 * 64];
    short* As = LB;
    short* Bs = LB + 128 * 64;
    const int m0 = blockIdx.x * 128, n0 = blockIdx.y * 128;
    floatx4 acc[4][4] = {};
    gemm_main(Cb, WoT, As, Bs, m0, n0, acc, threadIdx.x);

    const int tid = threadIdx.x, wave = tid >> 6, lane = tid & 63;
    const int ln = lane & 15, quad = lane >> 4;
    const int mw = (wave & 1) * 64, nw = (wave >> 1) * 64;
    for (int i = 0; i < 4; i++)
        for (int j = 0; j < 4; j++)
            for (int r = 0; r < 4; r++) {
                const int row = m0 + mw + i * 16 + quad * 4 + r;
                const int col = n0 + nw + j * 16 + ln;
                out[(size_t)row * D_DIM + col] = acc[i][j][r] + bias[col];
            }
}

// ---------------- causal flash attention: S^T form, 128-key tiles ----------------
// Scores arrive pre-scaled by log2(e) (Q scaled at projection).
// 1536 blocks; qt>=16 split into 2 key chunks (fp32 partials); LPT-ish order;
// id&7==bh&7 XCD affinity (4 heads/XCD -> 2 MB K+V in 4 MB L2).
#define PST 136   // Ps stride (shorts)

__global__ __launch_bounds__(256, 3) void attn_kernel(const short* __restrict__ Q,
                                                      const short* __restrict__ Kg,
                                                      const short* __restrict__ Vt,
                                                      short* __restrict__ ctx,
                                                      float* __restrict__ Opart,
                                                      float* __restrict__ Mlpart) {
    __shared__ __align__(16) short Ks[128 * 64];      // [key][hd]
    __shared__ __align__(16) short Vs[64 * 128];      // [hd][key]
    __shared__ __align__(16) short Ps[4][16 * PST];   // per-wave staging

    const int tid = threadIdx.x, wave = tid >> 6, lane = tid & 63;
    const int ln = lane & 15, quad = lane >> 4;

    const int id = blockIdx.x;            // 0..1535
    const int bh = (id & 7) + 8 * ((id >> 3) & 3);
    const int t = id >> 5;                // 0..47
    int qt, k_begin, k_end, pidx;
    if (t < 32) {                         // split tasks, qt = 31..16
        qt = 31 - (t >> 1);
        const int half = t & 1;
        const int n = (qt + 2) >> 1;      // ceil((qt+1)/2) 128-key tiles
        const int h0 = n >> 1;
        k_begin = half ? h0 : 0;
        k_end   = half ? n  : h0;
        pidx = ((qt - 16) * 32 + bh) * 2 + half;
    } else {                              // unsplit, qt = 15..0
        qt = 47 - t;
        k_begin = 0; k_end = (qt + 2) >> 1;
        pidx = -1;
    }
    const int kmask = ((qt + 2) >> 1) - 1;   // tile containing the diagonal
    const int q0 = qt * 64;
    const int bb = bh >> 4, h = bh & 15;
    short* Pw = &Ps[wave][0];

    const short* qrow = Q + ((size_t)bh * S_LEN + q0 + wave * 16 + ln) * HD;
    const short8 qb0 = *(const short8*)(qrow + quad * 8);
    const short8 qb1 = *(const short8*)(qrow + 32 + quad * 8);
    const int q_abs = q0 + wave * 16 + ln;

    float m_run = -INFINITY, l_run = 0.f;
    floatx4 o_acc[4] = {};

    for (int kt = k_begin; kt < k_end; kt++) {
        const int k0 = kt * 128;
        __syncthreads();
        for (int tt = 0; tt < 4; tt++) {
            const int c = tt * 256 + tid;
            {   // K tile: 128 rows x 64 hd
                const int row = c >> 3, pos = c & 7, src = pos ^ (row & 7);
                gll16(Kg + ((size_t)bh * S_LEN + k0 + row) * HD + src * 8, Ks + c * 8);
            }
            {   // V^T tile: 64 rows x 128 keys
                const int row = c >> 4, pos = c & 15, src = pos ^ (row & 15);
                gll16(Vt + ((size_t)bh * HD + row) * S_LEN + k0 + src * 8, Vs + c * 8);
            }
        }
        __syncthreads();

        // S^T: D[m=key(nt*16+quad*4+r)][n=query(ln)], 8 tiles over 128 keys
        floatx4 sc[8];
        for (int nt = 0; nt < 8; nt++) {
            const int row = nt * 16 + ln;
            const short8 ak0 = *(const short8*)(Ks + row * 64 + ((quad ^ (ln & 7)) * 8));
            const short8 ak1 = *(const short8*)(Ks + row * 64 + (((4 + quad) ^ (ln & 7)) * 8));
            floatx4 z = {};
            z = __builtin_amdgcn_mfma_f32_16x16x32_bf16(ak0, qb0, z, 0, 0, 0);
            z = __builtin_amdgcn_mfma_f32_16x16x32_bf16(ak1, qb1, z, 0, 0, 0);
            sc[nt] = z;
        }

        if (kt == kmask) {  // diagonal tile: mask key > query
            for (int nt = 0; nt < 8; nt++)
                for (int r = 0; r < 4; r++)
                    if (k0 + nt * 16 + quad * 4 + r > q_abs) sc[nt][r] = -1e30f;
        }

        // online softmax (log2 domain): 32 in-lane values + 2 cross-quad shuffles
        float mt = sc[0][0];
        for (int nt = 0; nt < 8; nt++)
            for (int r = 0; r < 4; r++) mt = fmaxf(mt, sc[nt][r]);
        mt = fmaxf(mt, __shfl_xor(mt, 16, 64));
        mt = fmaxf(mt, __shfl_xor(mt, 32, 64));
        const float mnew = fmaxf(m_run, mt);
        if (__ballot(mnew > m_run)) {       // rescale only when some lane has a new max
            const float alpha = exp2f(m_run - mnew);
            l_run *= alpha;
            for (int dt = 0; dt < 4; dt++)
                for (int r = 0; r < 4; r++) o_acc[dt][r] *= alpha;
            m_run = mnew;
        }
        float ls = 0.f;
        for (int nt = 0; nt < 8; nt++)
            for (int r = 0; r < 4; r++) {
                const float e = exp2f(sc[nt][r] - m_run);
                sc[nt][r] = e; ls += e;
            }
        ls += __shfl_xor(ls, 16, 64);
        ls += __shfl_xor(ls, 32, 64);
        l_run += ls;

        // P^T -> B-operand layout via wave-private LDS [q=ln][key]
        for (int nt = 0; nt < 8; nt++) {
            uint2 u;
            u.x = pack2(sc[nt][0], sc[nt][1]);
            u.y = pack2(sc[nt][2], sc[nt][3]);
            *(uint2*)&Pw[ln * PST + nt * 16 + quad * 4] = u;
        }

        // O^T += V^T · P^T : D[m=d][n=q], K-dim = 128 keys (4 MFMA steps)
        for (int ks = 0; ks < 4; ks++) {
            const short8 bp = *(const short8*)&Pw[ln * PST + ks * 32 + quad * 8];
            for (int dt = 0; dt < 4; dt++) {
                const int row = dt * 16 + ln;
                const short8 av = *(const short8*)(Vs + row * 128 + (((ks * 4 + quad) ^ (ln & 15)) * 8));
                o_acc[dt] = __builtin_amdgcn_mfma_f32_16x16x32_bf16(av, bp, o_acc[dt], 0, 0, 0);
            }
        }
    }

    if (pidx >= 0) {
        float* Ob = Opart + (size_t)pidx * 4096 + (wave * 16 + ln) * 64;
        for (int dt = 0; dt < 4; dt++)
            *(float4*)(Ob + dt * 16 + quad * 4) = *(float4*)&o_acc[dt];
        if (quad == 0) {
            Mlpart[(size_t)pidx * 128 + wave * 16 + ln]      = m_run;
            Mlpart[(size_t)pidx * 128 + 64 + wave * 16 + ln] = l_run;
        }
    } else {
        const float rl = 1.f / l_run;
        for (int dt = 0; dt < 4; dt++) {
            uint2 u;
            u.x = pack2(o_acc[dt][0] * rl, o_acc[dt][1] * rl);
            u.y = pack2(o_acc[dt][2] * rl, o_acc[dt][3] * rl);
            *(uint2*)&Pw[ln * PST + dt * 16 + quad * 4] = u;   // [q=ln][d]
        }
        const int qr = lane >> 2, sg = lane & 3;
        for (int c = 0; c < 2; c++) {
            const short8 v = *(const short8*)&Pw[qr * PST + sg * 8 + c * 32];
            const int s = q0 + wave * 16 + qr;
            *(short8*)(ctx + ((size_t)bb * S_LEN + s) * D_DIM + h * HD + sg * 8 + c * 32) = v;
        }
    }
}

// ---------------- combine split partials -> ctx (log2-domain m) ----------------
__global__ __launch_bounds__(256) void combine_kernel(const float* __restrict__ Opart,
                                                      const float* __restrict__ Mlpart,
                                                      short* __restrict__ ctx) {
    const int tile = blockIdx.x;          // 0..511
    const int qt = 16 + (tile >> 5), bh = tile & 31;
    const int bb = bh >> 4, h = bh & 15;
    const int p0 = ((qt - 16) * 32 + bh) * 2;
    const float* O0 = Opart + (size_t)p0 * 4096;
    const float* O1 = O0 + 4096;
    const float* ml0 = Mlpart + (size_t)p0 * 128;
    const float* ml1 = ml0 + 128;
    for (int e = threadIdx.x; e < 1024; e += 256) {
        const int q = e >> 4, dseg = e & 15;
        const float m0 = ml0[q], l0 = ml0[64 + q];
        const float m1 = ml1[q], l1 = ml1[64 + q];
        const float m = fmaxf(m0, m1);
        const float a0 = exp2f(m0 - m), a1 = exp2f(m1 - m);
        const float rl = 1.f / (l0 * a0 + l1 * a1);
        const float4 x0 = *(const float4*)(O0 + q * 64 + dseg * 4);
        const float4 x1 = *(const float4*)(O1 + q * 64 + dseg * 4);
        uint2 u;
        u.x = pack2((x0.x * a0 + x1.x * a1) * rl, (x0.y * a0 + x1.y * a1) * rl);
        u.y = pack2((x0.z * a0 + x1.z * a1) * rl, (x0.w * a0 + x1.w * a1) * rl);
        const int s = qt * 64 + q;
        *(uint2*)(ctx + ((size_t)bb * S_LEN + s) * D_DIM + h * HD + dseg * 4) = u;
    }
}

// ---------------- launch ----------------
extern "C" void kernel_launch(void* const* d_in, const int* in_sizes, int n_in,
                              void* d_out, int out_size, void* d_ws, size_t ws_size,
                              hipStream_t stream) {
    const float* X  = (const float*)d_in[0];
    const float* Wq = (const float*)d_in[1];
    const float* Wk = (const float*)d_in[2];
    const float* Wv = (const float*)d_in[3];
    const float* Wo = (const float*)d_in[4];
    const float* bo = (const float*)d_in[5];
    float* out = (float*)d_out;

    char* ws = (char*)d_ws;
    const size_t MB = 1024 * 1024;
    short* Xb     = (short*)(ws);                 //  0- 8 MB (dead after QKV GEMM)
    short* WqkvT  = (short*)(ws + 8  * MB);       //  8-14 MB (dead after QKV GEMM)
    short* Qb     = (short*)(ws + 16 * MB);       // 16-24 MB [B,H,S,HD] (Q pre-scaled by log2e)
    short* Kb     = (short*)(ws + 24 * MB);       // 24-32 MB [B,H,S,HD]
    short* Vtb    = (short*)(ws + 32 * MB);       // 32-40 MB [B,H,HD,S]
    short* ctxb   = (short*)(ws + 40 * MB);       // 40-48 MB [4096][1024]
    short* WoT    = (short*)(ws + 48 * MB);       // 48-50 MB
    float* Opart  = (float*)(ws);                 //  0- 8 MB, reuses dead region
    float* Mlpart = (float*)(ws + 50 * MB);       // 50-50.5 MB

    castx_kernel<<<4096, 256, 0, stream>>>(X, Xb);
    dim3 tg(32, 32, 4), tb(32, 8);
    tcast4_kernel<<<tg, tb, 0, stream>>>(Wq, Wk, Wv, Wo, WqkvT, WoT);

    dim3 gq(32, 24);   // M=4096/128, N=3072/128
    gemm_qkv_kernel<<<gq, 256, 0, stream>>>(Xb, WqkvT, Qb, Kb, Vtb);

    attn_kernel<<<1536, 256, 0, stream>>>(Qb, Kb, Vtb, ctxb, Opart, Mlpart);
    combine_kernel<<<512, 256, 0, stream>>>(Opart, Mlpart, ctxb);

    dim3 go(32, 8);
    gemm_out_kernel<<<go, 256, 0, stream>>>(ctxb, WoT, out, bo);
}